// Round 13
// baseline (734.665 us; speedup 1.0000x reference)
//
#include <hip/hip_runtime.h>

#define N_NODES 50000
#define N_EDGES 800000
#define N_GRAPHS 50
#define D 128
#define D_OUT 10
#define PLANE_F4 200000   // per-slice plane: 50000 nodes * 4 float4 (16 floats)
#define NB 196            // coarse buckets: dst>>8 (49999>>8 == 195)
#define NBLK 196          // partition blocks (196*4096 >= 800000)
#define LCOL_CAP 3072     // staged cols per block (mean 1024, sigma ~32)
#define AST 68            // padded LDS stride (words): q-stride 272%32=16 -> 2-way

// ---------------------------------------------------------------------------
// 1) Coarse partition histogram for dst (LDS atomics only). The src
//    out-degree atomics live in part_scatter (overlap the vector pipes).
// ---------------------------------------------------------------------------
__global__ __launch_bounds__(256) void part_hist(const int* __restrict__ dst,
                                                 int* __restrict__ gh) {
    __shared__ int lh[NB];
    int tid = threadIdx.x, blk = blockIdx.x;
    if (tid < NB) lh[tid] = 0;
    __syncthreads();
    int base = blk * 4096;
    #pragma unroll
    for (int j = 0; j < 16; j++) {
        int i = base + j * 256 + tid;
        if (i < N_EDGES) atomicAdd(&lh[dst[i] >> 8], 1);     // LDS atomic
    }
    __syncthreads();
    if (tid < NB) gh[tid * NBLK + blk] = lh[tid];
}

// ---------------------------------------------------------------------------
// 2) Exclusive scan of gh[NB*NBLK = 38416]: round-3 chunked version
//    (coalesced: thread t loads base+t*4..+3).
// ---------------------------------------------------------------------------
__global__ __launch_bounds__(1024) void part_scan(int* __restrict__ gh) {
    __shared__ int wsum[16];
    __shared__ int carry_s;
    const int N = NB * NBLK;            // 38416
    int tid = threadIdx.x;
    int lane = tid & 63, wid = tid >> 6;
    if (tid == 0) carry_s = 0;
    __syncthreads();
    for (int base = 0; base < N; base += 4096) {
        int i0 = base + tid * 4;
        int v0 = (i0 + 0 < N) ? gh[i0 + 0] : 0;
        int v1 = (i0 + 1 < N) ? gh[i0 + 1] : 0;
        int v2 = (i0 + 2 < N) ? gh[i0 + 2] : 0;
        int v3 = (i0 + 3 < N) ? gh[i0 + 3] : 0;
        int s = v0 + v1 + v2 + v3;
        int x = s;
        #pragma unroll
        for (int d = 1; d < 64; d <<= 1) {
            int y = __shfl_up(x, d, 64);
            if (lane >= d) x += y;
        }
        if (lane == 63) wsum[wid] = x;
        __syncthreads();
        if (wid == 0) {
            int t = (lane < 16) ? wsum[lane] : 0;
            #pragma unroll
            for (int d = 1; d < 16; d <<= 1) {
                int y = __shfl_up(t, d, 64);
                if (lane >= d) t += y;
            }
            if (lane < 16) wsum[lane] = t;
        }
        __syncthreads();
        int woff = (wid == 0) ? 0 : wsum[wid - 1];
        int run = carry_s + woff + (x - s);
        if (i0 + 0 < N) gh[i0 + 0] = run; run += v0;
        if (i0 + 1 < N) gh[i0 + 1] = run; run += v1;
        if (i0 + 2 < N) gh[i0 + 2] = run; run += v2;
        if (i0 + 3 < N) gh[i0 + 3] = run; run += v3;
        __syncthreads();
        if (tid == 0) carry_s += wsum[15];
        __syncthreads();
    }
}

// ---------------------------------------------------------------------------
// 3) Partition scatter (LDS cursors) + src out-degree histogram riding the
//    otherwise-idle device-atomic pipe.
// ---------------------------------------------------------------------------
__global__ __launch_bounds__(256) void part_scatter(const int* __restrict__ src,
                                                    const int* __restrict__ dst,
                                                    const int* __restrict__ gh,
                                                    unsigned int* __restrict__ packed,
                                                    int* __restrict__ out_deg) {
    __shared__ int lc[NB];
    int tid = threadIdx.x, blk = blockIdx.x;
    if (tid < NB) lc[tid] = gh[tid * NBLK + blk];
    __syncthreads();
    int base = blk * 4096;
    #pragma unroll
    for (int j = 0; j < 16; j++) {
        int i = base + j * 256 + tid;
        if (i < N_EDGES) {
            int d = dst[i];
            int s = src[i];
            atomicAdd(&out_deg[s], 1);               // device atomic (src stream)
            int p = atomicAdd(&lc[d >> 8], 1);       // LDS atomic
            packed[p] = ((unsigned int)(d & 255) << 16) | (unsigned int)s;
        }
    }
}

// ---------------------------------------------------------------------------
// 4) Per-bucket CSR build: one block per coarse bucket (~4096 edges, <=8192).
// ---------------------------------------------------------------------------
__global__ __launch_bounds__(256) void bucket_csr(const unsigned int* __restrict__ packed,
                                                  const int* __restrict__ gh,
                                                  unsigned short* __restrict__ col16,
                                                  int* __restrict__ row_ptr,
                                                  float* __restrict__ nd) {
    __shared__ unsigned int ep[8192];
    __shared__ unsigned short lcol[8192];
    __shared__ int hist[256], cur[256], wsum[4];
    int t = threadIdx.x, b = blockIdx.x;
    int nb = gh[b * NBLK];
    int ne = (b < NB - 1) ? gh[(b + 1) * NBLK] : N_EDGES;
    int cnt = ne - nb;
    if (cnt > 8192) cnt = 8192;         // statistically unreachable guard
    hist[t] = 0;
    __syncthreads();
    for (int i = t; i < cnt; i += 256) {
        unsigned int e = packed[nb + i];
        ep[i] = e;
        atomicAdd(&hist[e >> 16], 1);
    }
    __syncthreads();
    int v = hist[t];
    int lane = t & 63, w = t >> 6;
    int x = v;
    #pragma unroll
    for (int d = 1; d < 64; d <<= 1) {
        int y = __shfl_up(x, d, 64);
        if (lane >= d) x += y;
    }
    if (lane == 63) wsum[w] = x;
    __syncthreads();
    int add = 0;
    #pragma unroll
    for (int i = 0; i < 4; i++) if (i < w) add += wsum[i];
    int excl = add + x - v;
    cur[t] = excl;
    int node = b * 256 + t;
    if (node < N_NODES) {
        row_ptr[node] = nb + excl;
        int id = v > 1 ? v : 1;
        nd[node] = 1.0f / sqrtf((float)id);
    }
    if (b == NB - 1 && t == 0) row_ptr[N_NODES] = N_EDGES;
    __syncthreads();
    for (int i = t; i < cnt; i += 256) {
        unsigned int e = ep[i];
        int p = atomicAdd(&cur[e >> 16], 1);         // LDS atomic
        lcol[p] = (unsigned short)(e & 0xFFFF);
    }
    __syncthreads();
    for (int i = t; i < cnt; i += 256) col16[nb + i] = lcol[i];
}

// ---------------------------------------------------------------------------
// 5) Prescale + slice: xs[p][node][16] = out_deg[node]^-1/2 * h[node][p*16..].
// ---------------------------------------------------------------------------
__global__ __launch_bounds__(256) void prescale_k(const float* __restrict__ h,
                                                  const int* __restrict__ out_deg,
                                                  float* __restrict__ out) {
    int i = blockIdx.x * 256 + threadIdx.x;      // over 1,600,000 float4s
    if (i < N_NODES * 32) {
        int node = i >> 5;
        int kg = i & 31;
        float4 v = ((const float4*)h)[i];
        int od = out_deg[node];
        float s = 1.0f / sqrtf((float)(od > 1 ? od : 1));
        int p = kg >> 2, q = kg & 3;
        ((float4*)out)[p * PLANE_F4 + node * 4 + q] =
            make_float4(v.x * s, v.y * s, v.z * s, v.w * s);
    }
}

// ---------------------------------------------------------------------------
// 6) Feature-sliced SpMM with LDS col staging (round-9 version, unchanged).
//    Shape LOCKED: grid 6256, 256 threads, slice=b&7, 64 nodes/blk.
// ---------------------------------------------------------------------------
__global__ __launch_bounds__(256) void spmm_k(const float* __restrict__ x,   // sliced
                                              const int* __restrict__ row_ptr,
                                              const unsigned short* __restrict__ col,
                                              const float* __restrict__ nd,
                                              float* __restrict__ out) {     // sliced
    __shared__ unsigned short lcol[LCOL_CAP];
    int b = blockIdx.x;
    int slice = b & 7;
    int n0b = (b >> 3) * 64;
    int nendb = n0b + 64; if (nendb > N_NODES) nendb = N_NODES;
    int e0 = row_ptr[n0b];
    int e1 = row_ptr[nendb];
    int cnt = e1 - e0;
    int staged = cnt < LCOL_CAP ? cnt : LCOL_CAP;
    for (int j = threadIdx.x; j < staged; j += 256) lcol[j] = col[e0 + j];
    __syncthreads();

    int node = n0b + (threadIdx.x >> 2);
    if (node >= N_NODES) return;
    int q = threadIdx.x & 3;
    int s = row_ptr[node];
    int e = row_ptr[node + 1];
    const float4* xp = (const float4*)x + slice * PLANE_F4;
    float4 a0 = make_float4(0.f, 0.f, 0.f, 0.f);
    float4 a1 = make_float4(0.f, 0.f, 0.f, 0.f);
    float4 a2 = make_float4(0.f, 0.f, 0.f, 0.f);
    float4 a3 = make_float4(0.f, 0.f, 0.f, 0.f);

    if (e - e0 <= staged) {
        const unsigned short* lc = lcol + (s - e0);
        int n = e - s;
        int i = 0;
        for (; i + 8 <= n; i += 8) {
            int c0 = lc[i],     c1 = lc[i + 1], c2 = lc[i + 2], c3 = lc[i + 3];
            int c4 = lc[i + 4], c5 = lc[i + 5], c6 = lc[i + 6], c7 = lc[i + 7];
            float4 h0 = xp[c0 * 4 + q];
            float4 h1 = xp[c1 * 4 + q];
            float4 h2 = xp[c2 * 4 + q];
            float4 h3 = xp[c3 * 4 + q];
            float4 h4 = xp[c4 * 4 + q];
            float4 h5 = xp[c5 * 4 + q];
            float4 h6 = xp[c6 * 4 + q];
            float4 h7 = xp[c7 * 4 + q];
            a0.x += h0.x; a0.y += h0.y; a0.z += h0.z; a0.w += h0.w;
            a1.x += h1.x; a1.y += h1.y; a1.z += h1.z; a1.w += h1.w;
            a2.x += h2.x; a2.y += h2.y; a2.z += h2.z; a2.w += h2.w;
            a3.x += h3.x; a3.y += h3.y; a3.z += h3.z; a3.w += h3.w;
            a0.x += h4.x; a0.y += h4.y; a0.z += h4.z; a0.w += h4.w;
            a1.x += h5.x; a1.y += h5.y; a1.z += h5.z; a1.w += h5.w;
            a2.x += h6.x; a2.y += h6.y; a2.z += h6.z; a2.w += h6.w;
            a3.x += h7.x; a3.y += h7.y; a3.z += h7.z; a3.w += h7.w;
        }
        for (; i + 4 <= n; i += 4) {
            int c0 = lc[i], c1 = lc[i + 1], c2 = lc[i + 2], c3 = lc[i + 3];
            float4 h0 = xp[c0 * 4 + q];
            float4 h1 = xp[c1 * 4 + q];
            float4 h2 = xp[c2 * 4 + q];
            float4 h3 = xp[c3 * 4 + q];
            a0.x += h0.x; a0.y += h0.y; a0.z += h0.z; a0.w += h0.w;
            a1.x += h1.x; a1.y += h1.y; a1.z += h1.z; a1.w += h1.w;
            a2.x += h2.x; a2.y += h2.y; a2.z += h2.z; a2.w += h2.w;
            a3.x += h3.x; a3.y += h3.y; a3.z += h3.z; a3.w += h3.w;
        }
        for (; i < n; i++) {
            float4 hv = xp[lc[i] * 4 + q];
            a0.x += hv.x; a0.y += hv.y; a0.z += hv.z; a0.w += hv.w;
        }
    } else {
        int i = s;
        for (; i + 4 <= e; i += 4) {
            int c0 = col[i], c1 = col[i + 1], c2 = col[i + 2], c3 = col[i + 3];
            float4 h0 = xp[c0 * 4 + q];
            float4 h1 = xp[c1 * 4 + q];
            float4 h2 = xp[c2 * 4 + q];
            float4 h3 = xp[c3 * 4 + q];
            a0.x += h0.x; a0.y += h0.y; a0.z += h0.z; a0.w += h0.w;
            a1.x += h1.x; a1.y += h1.y; a1.z += h1.z; a1.w += h1.w;
            a2.x += h2.x; a2.y += h2.y; a2.z += h2.z; a2.w += h2.w;
            a3.x += h3.x; a3.y += h3.y; a3.z += h3.z; a3.w += h3.w;
        }
        for (; i < e; i++) {
            float4 hv = xp[col[i] * 4 + q];
            a0.x += hv.x; a0.y += hv.y; a0.z += hv.z; a0.w += hv.w;
        }
    }
    float ndv = nd[node];
    ((float4*)out)[slice * PLANE_F4 + node * 4 + q] =
        make_float4((a0.x + a1.x + a2.x + a3.x) * ndv,
                    (a0.y + a1.y + a2.y + a3.y) * ndv,
                    (a0.z + a1.z + a2.z + a3.z) * ndv,
                    (a0.w + a1.w + a2.w + a3.w) * ndv);
}

// ---------------------------------------------------------------------------
// 7) GEMM + bias + ReLU. ROUND-13: manual register double-buffer of the
//    k-loop loads. Evidence: r9-r12 pinned at 52us / VALUBusy ~23% across
//    four geometries; VALU issue floor is 10.4us -> waves wait ~430cy per
//    k-iteration = the full W-global(~200cy) + A-LDS(~120cy) chain exposed
//    every k (compiler not pipelining; 1.5 waves/SIMD can't mask). Fix:
//    two register sets, consume-then-prefetch k+2 (branchless &127 clamp),
//    k+=2 loop, no register rotation. Geometry unchanged from r12 (proven
//    non-lever): 64x128 tile, 128 threads, 8x8/thread, grid 782, AST=68.
//    MODE 0: out = odeg^-1/2 * relu(A@W+b), SLICED. MODE 1: normal layout.
// ---------------------------------------------------------------------------
template <int MODE>
__global__ __launch_bounds__(128) void gemm_relu_k(const float* __restrict__ A,  // sliced
                                                   const float* __restrict__ W,
                                                   const float* __restrict__ bias,
                                                   const int* __restrict__ odeg,
                                                   float* __restrict__ out) {
    __shared__ float As_t[128 * AST];   // 34,816 B: [k][r], padded stride 68
    int tid = threadIdx.x;
    int row0 = blockIdx.x * 64;
    const float4* A4 = (const float4*)A;
    const float4* W4 = (const float4*)W;

    // stage A: 64 rows x 128 k = 2048 float4s, 16 per thread
    #pragma unroll
    for (int it = 0; it < 16; it++) {
        int linear = it * 128 + tid;       // 0..2047
        int p = linear >> 8;               // plane 0..7
        int rem = linear & 255;
        int r = rem >> 2;                  // local row 0..63
        int q = rem & 3;                   // float4 within 16-float slice
        int row = row0 + r;
        float4 a = (row < N_NODES) ? A4[p * PLANE_F4 + row * 4 + q]
                                   : make_float4(0.f, 0.f, 0.f, 0.f);
        int kb = p * 16 + q * 4;
        As_t[(kb + 0) * AST + r] = a.x;
        As_t[(kb + 1) * AST + r] = a.y;
        As_t[(kb + 2) * AST + r] = a.z;
        As_t[(kb + 3) * AST + r] = a.w;
    }
    __syncthreads();

    int tc = tid & 15;    // col group: cols tc*8 .. +8 (of 128)
    int tr = tid >> 4;    // 0..7 : rows tr*8 .. +8 (of 64)
    float acc[8][8];
    #pragma unroll
    for (int r = 0; r < 8; r++)
        #pragma unroll
        for (int c = 0; c < 8; c++) acc[r][c] = 0.f;

    const float4* Wp = W4 + tc * 2;          // Wp[k*32] = W[k][tc*8..]
    const float*  Ab = As_t + tr * 8;        // Ab[k*AST] = A[k][tr*8..]

    // preload k=0 (set A) and k=1 (set B)
    float4 w0A = Wp[0],  w1A = Wp[1];
    float4 w0B = Wp[32], w1B = Wp[33];
    float4 a0A = *(const float4*)(Ab);
    float4 a1A = *(const float4*)(Ab + 4);
    float4 a0B = *(const float4*)(Ab + AST);
    float4 a1B = *(const float4*)(Ab + AST + 4);

    for (int k = 0; k < 128; k += 2) {
        // ---- consume set A (iteration k) ----
        {
            float av[8] = {a0A.x, a0A.y, a0A.z, a0A.w, a1A.x, a1A.y, a1A.z, a1A.w};
            float wv[8] = {w0A.x, w0A.y, w0A.z, w0A.w, w1A.x, w1A.y, w1A.z, w1A.w};
            #pragma unroll
            for (int rr = 0; rr < 8; rr++)
                #pragma unroll
                for (int cc = 0; cc < 8; cc++)
                    acc[rr][cc] = fmaf(av[rr], wv[cc], acc[rr][cc]);
        }
        // prefetch set A for k+2 (branchless wrap keeps addresses in-bounds;
        // wrapped values are never consumed)
        {
            int kp = (k + 2) & 127;
            w0A = Wp[kp * 32]; w1A = Wp[kp * 32 + 1];
            a0A = *(const float4*)(Ab + kp * AST);
            a1A = *(const float4*)(Ab + kp * AST + 4);
        }
        // ---- consume set B (iteration k+1) ----
        {
            float av[8] = {a0B.x, a0B.y, a0B.z, a0B.w, a1B.x, a1B.y, a1B.z, a1B.w};
            float wv[8] = {w0B.x, w0B.y, w0B.z, w0B.w, w1B.x, w1B.y, w1B.z, w1B.w};
            #pragma unroll
            for (int rr = 0; rr < 8; rr++)
                #pragma unroll
                for (int cc = 0; cc < 8; cc++)
                    acc[rr][cc] = fmaf(av[rr], wv[cc], acc[rr][cc]);
        }
        // prefetch set B for k+3
        {
            int kp = (k + 3) & 127;
            w0B = Wp[kp * 32]; w1B = Wp[kp * 32 + 1];
            a0B = *(const float4*)(Ab + kp * AST);
            a1B = *(const float4*)(Ab + kp * AST + 4);
        }
    }

    float4 bv0 = ((const float4*)bias)[tc * 2];
    float4 bv1 = ((const float4*)bias)[tc * 2 + 1];
    #pragma unroll
    for (int rr = 0; rr < 8; rr++) {
        int row = row0 + tr * 8 + rr;
        if (row < N_NODES) {
            float4 o0, o1;
            o0.x = fmaxf(acc[rr][0] + bv0.x, 0.f);
            o0.y = fmaxf(acc[rr][1] + bv0.y, 0.f);
            o0.z = fmaxf(acc[rr][2] + bv0.z, 0.f);
            o0.w = fmaxf(acc[rr][3] + bv0.w, 0.f);
            o1.x = fmaxf(acc[rr][4] + bv1.x, 0.f);
            o1.y = fmaxf(acc[rr][5] + bv1.y, 0.f);
            o1.z = fmaxf(acc[rr][6] + bv1.z, 0.f);
            o1.w = fmaxf(acc[rr][7] + bv1.w, 0.f);
            if (MODE == 0) {
                int od = odeg[row];
                float s = 1.0f / sqrtf((float)(od > 1 ? od : 1));
                o0.x *= s; o0.y *= s; o0.z *= s; o0.w *= s;
                o1.x *= s; o1.y *= s; o1.z *= s; o1.w *= s;
                int p = tc >> 1;
                int q0 = (tc & 1) * 2;
                ((float4*)out)[p * PLANE_F4 + row * 4 + q0] = o0;
                ((float4*)out)[p * PLANE_F4 + row * 4 + q0 + 1] = o1;
            } else {
                ((float4*)out)[row * 32 + tc * 2] = o0;
                ((float4*)out)[row * 32 + tc * 2 + 1] = o1;
            }
        }
    }
}

// ---------------------------------------------------------------------------
// 8) Fused projection + readout (unchanged).
// ---------------------------------------------------------------------------
__global__ __launch_bounds__(256) void proj_readout_k(const float* __restrict__ h,
                                                      const int* __restrict__ gid,
                                                      const float* __restrict__ Wm,
                                                      float* __restrict__ hgp,
                                                      int* __restrict__ gcnt) {
    __shared__ float Wmt[10 * 144];
    int tid = threadIdx.x;
    for (int i = tid; i < 1280; i += 256) {
        int k = i / 10, o = i % 10;
        Wmt[o * 144 + k + 4 * (k >> 5)] = Wm[i];
    }
    __syncthreads();

    int v = blockIdx.x * 64 + (tid >> 2);
    int quarter = tid & 3;
    int lane = tid & 63;

    float acc[D_OUT];
    #pragma unroll
    for (int o = 0; o < D_OUT; o++) acc[o] = 0.f;
    int g = -1;
    int cnt = 0;
    if (v < N_NODES) {
        g = gid[v];
        cnt = (quarter == 0) ? 1 : 0;
        const float4* h4 = (const float4*)h + v * 32 + quarter * 8;
        const float* wbase = Wmt + quarter * 36;
        #pragma unroll
        for (int kk = 0; kk < 8; kk++) {
            float4 hv = h4[kk];
            #pragma unroll
            for (int o = 0; o < D_OUT; o++) {
                float4 w = *(const float4*)(wbase + o * 144 + kk * 4);
                acc[o] += hv.x * w.x + hv.y * w.y + hv.z * w.z + hv.w * w.w;
            }
        }
    }

    #pragma unroll
    for (int d = 1; d < 64; d <<= 1) {
        int gp = __shfl_up(g, d, 64);
        int cp = __shfl_up(cnt, d, 64);
        bool take = (lane >= d) && (gp == g);
        #pragma unroll
        for (int o = 0; o < D_OUT; o++) {
            float ap = __shfl_up(acc[o], d, 64);
            if (take) acc[o] += ap;
        }
        if (take) cnt += cp;
    }
    int gn = __shfl_down(g, 1, 64);
    bool tail = (lane == 63) || (gn != g);
    if (tail && g >= 0) {
        #pragma unroll
        for (int o = 0; o < D_OUT; o++) atomicAdd(&hgp[g * D_OUT + o], acc[o]);
        if (cnt > 0) atomicAdd(&gcnt[g], cnt);
    }
}

// ---------------------------------------------------------------------------
// 9) Final: logits = hgp/cnt + bm ; log_softmax over axis 0 (graphs)
// ---------------------------------------------------------------------------
__global__ __launch_bounds__(512) void final_k(const float* __restrict__ hgp,
                                               const int* __restrict__ gcnt,
                                               const float* __restrict__ bm,
                                               float* __restrict__ out) {
    __shared__ float lg[N_GRAPHS * D_OUT];
    __shared__ float colm[D_OUT], colls[D_OUT];
    int tid = threadIdx.x;
    if (tid < N_GRAPHS * D_OUT) {
        int g = tid / D_OUT, o = tid % D_OUT;
        float c = (float)gcnt[g];
        lg[tid] = hgp[tid] / (c > 1.f ? c : 1.f) + bm[o];
    }
    __syncthreads();
    if (tid < D_OUT) {
        float m = -1e30f;
        for (int g = 0; g < N_GRAPHS; g++) m = fmaxf(m, lg[g * D_OUT + tid]);
        float s = 0.f;
        for (int g = 0; g < N_GRAPHS; g++) s += expf(lg[g * D_OUT + tid] - m);
        colm[tid] = m; colls[tid] = logf(s);
    }
    __syncthreads();
    if (tid < N_GRAPHS * D_OUT) {
        int o = tid % D_OUT;
        out[tid] = lg[tid] - colm[o] - colls[o];
    }
}

// ---------------------------------------------------------------------------
// Launch. packed[] aliases bufB head (dead before spmm#1 writes bufB).
// Total footprint 53,556,128 B.
// ---------------------------------------------------------------------------
extern "C" void kernel_launch(void* const* d_in, const int* in_sizes, int n_in,
                              void* d_out, int out_size, void* d_ws, size_t ws_size,
                              hipStream_t stream) {
    const float* h_in = (const float*)d_in[0];
    const int*   src  = (const int*)d_in[1];
    const int*   dst  = (const int*)d_in[2];
    const int*   gid  = (const int*)d_in[3];
    const float* W1 = (const float*)d_in[4];  const float* b1 = (const float*)d_in[5];
    const float* W2 = (const float*)d_in[6];  const float* b2 = (const float*)d_in[7];
    const float* W3 = (const float*)d_in[8];  const float* b3 = (const float*)d_in[9];
    const float* Wm = (const float*)d_in[10]; const float* bm = (const float*)d_in[11];

    char* ws = (char*)d_ws;
    int*            row_ptr = (int*)(ws + 0);                     // 50001 ints (pad 200,032)
    unsigned short* col16   = (unsigned short*)(ws + 200032);     // 1,600,000 B
    float*          nd      = (float*)(ws + 1800032);             // 200,000 B
    int*            out_deg = (int*)(ws + 2000032);               // 200,000 B  } zeroed
    int*            gcnt    = (int*)(ws + 2200032);               // 256 B      } together
    float*          hgp     = (float*)(ws + 2200288);             // 2,048 B    } 202,432 B
    int*            gh      = (int*)(ws + 2202464);               // 153,664 B
    float*          bufA    = (float*)(ws + 2356128);             // 25.6 MB
    float*          bufB    = (float*)(ws + 27956128);            // 25.6 MB -> 53,556,128
    unsigned int*   packed  = (unsigned int*)bufB;                // 3.2 MB alias

    hipMemsetAsync(out_deg, 0, 202432, stream);     // out_deg+gcnt+hgp

    part_hist<<<NBLK, 256, 0, stream>>>(dst, gh);
    part_scan<<<1, 1024, 0, stream>>>(gh);
    part_scatter<<<NBLK, 256, 0, stream>>>(src, dst, gh, packed, out_deg);
    bucket_csr<<<NB, 256, 0, stream>>>(packed, gh, col16, row_ptr, nd);
    prescale_k<<<6250, 256, 0, stream>>>(h_in, out_deg, bufA);

    spmm_k<<<6256, 256, 0, stream>>>(bufA, row_ptr, col16, nd, bufB);
    gemm_relu_k<0><<<782, 128, 0, stream>>>(bufB, W1, b1, out_deg, bufA);
    spmm_k<<<6256, 256, 0, stream>>>(bufA, row_ptr, col16, nd, bufB);
    gemm_relu_k<0><<<782, 128, 0, stream>>>(bufB, W2, b2, out_deg, bufA);
    spmm_k<<<6256, 256, 0, stream>>>(bufA, row_ptr, col16, nd, bufB);
    gemm_relu_k<1><<<782, 128, 0, stream>>>(bufB, W3, b3, out_deg, bufA);

    proj_readout_k<<<782, 256, 0, stream>>>(bufA, gid, Wm, hgp, gcnt);
    final_k<<<1, 512, 0, stream>>>(hgp, gcnt, bm, (float*)d_out);
}

// Round 14
// 442.682 us; speedup vs baseline: 1.6596x; 1.6596x over previous
//
#include <hip/hip_runtime.h>

#define N_NODES 50000
#define N_EDGES 800000
#define N_GRAPHS 50
#define D 128
#define D_OUT 10
#define PLANE_F4 200000   // per-slice plane: 50000 nodes * 4 float4 (16 floats)
#define NB 196            // coarse buckets: dst>>8 (49999>>8 == 195)
#define NBLK 196          // partition blocks (196*4096 >= 800000)
#define LCOL_CAP 3072     // staged cols per block (mean 1024, sigma ~32)
#define AST 68            // padded LDS stride (words): q-stride 272%32=16 -> 2-way
#define ZWORDS 50576      // out_deg(50000) + gcnt(64) + hgp(512) contiguous words

// ---------------------------------------------------------------------------
// 1) Coarse partition histogram for dst (LDS atomics only) + zeroing of the
//    out_deg/gcnt/hgp region (replaces the hipMemsetAsync dispatch; this
//    kernel completes before part_scatter's atomics and proj_readout).
// ---------------------------------------------------------------------------
__global__ __launch_bounds__(256) void part_hist(const int* __restrict__ dst,
                                                 int* __restrict__ gh,
                                                 int* __restrict__ zbuf) {
    __shared__ int lh[NB];
    int tid = threadIdx.x, blk = blockIdx.x;
    int z = blk * 256 + tid;                  // 196*256 = 50176 threads
    if (z < ZWORDS) zbuf[z] = 0;
    z += 50176;
    if (z < ZWORDS) zbuf[z] = 0;
    if (tid < NB) lh[tid] = 0;
    __syncthreads();
    int base = blk * 4096;
    #pragma unroll
    for (int j = 0; j < 16; j++) {
        int i = base + j * 256 + tid;
        if (i < N_EDGES) atomicAdd(&lh[dst[i] >> 8], 1);     // LDS atomic
    }
    __syncthreads();
    if (tid < NB) gh[tid * NBLK + blk] = lh[tid];
}

// ---------------------------------------------------------------------------
// 2) Exclusive scan of gh[NB*NBLK = 38416]: round-3 chunked version
//    (coalesced: thread t loads base+t*4..+3).
// ---------------------------------------------------------------------------
__global__ __launch_bounds__(1024) void part_scan(int* __restrict__ gh) {
    __shared__ int wsum[16];
    __shared__ int carry_s;
    const int N = NB * NBLK;            // 38416
    int tid = threadIdx.x;
    int lane = tid & 63, wid = tid >> 6;
    if (tid == 0) carry_s = 0;
    __syncthreads();
    for (int base = 0; base < N; base += 4096) {
        int i0 = base + tid * 4;
        int v0 = (i0 + 0 < N) ? gh[i0 + 0] : 0;
        int v1 = (i0 + 1 < N) ? gh[i0 + 1] : 0;
        int v2 = (i0 + 2 < N) ? gh[i0 + 2] : 0;
        int v3 = (i0 + 3 < N) ? gh[i0 + 3] : 0;
        int s = v0 + v1 + v2 + v3;
        int x = s;
        #pragma unroll
        for (int d = 1; d < 64; d <<= 1) {
            int y = __shfl_up(x, d, 64);
            if (lane >= d) x += y;
        }
        if (lane == 63) wsum[wid] = x;
        __syncthreads();
        if (wid == 0) {
            int t = (lane < 16) ? wsum[lane] : 0;
            #pragma unroll
            for (int d = 1; d < 16; d <<= 1) {
                int y = __shfl_up(t, d, 64);
                if (lane >= d) t += y;
            }
            if (lane < 16) wsum[lane] = t;
        }
        __syncthreads();
        int woff = (wid == 0) ? 0 : wsum[wid - 1];
        int run = carry_s + woff + (x - s);
        if (i0 + 0 < N) gh[i0 + 0] = run; run += v0;
        if (i0 + 1 < N) gh[i0 + 1] = run; run += v1;
        if (i0 + 2 < N) gh[i0 + 2] = run; run += v2;
        if (i0 + 3 < N) gh[i0 + 3] = run; run += v3;
        __syncthreads();
        if (tid == 0) carry_s += wsum[15];
        __syncthreads();
    }
}

// ---------------------------------------------------------------------------
// 3) Partition scatter (LDS cursors) + src out-degree histogram riding the
//    otherwise-idle device-atomic pipe.
// ---------------------------------------------------------------------------
__global__ __launch_bounds__(256) void part_scatter(const int* __restrict__ src,
                                                    const int* __restrict__ dst,
                                                    const int* __restrict__ gh,
                                                    unsigned int* __restrict__ packed,
                                                    int* __restrict__ out_deg) {
    __shared__ int lc[NB];
    int tid = threadIdx.x, blk = blockIdx.x;
    if (tid < NB) lc[tid] = gh[tid * NBLK + blk];
    __syncthreads();
    int base = blk * 4096;
    #pragma unroll
    for (int j = 0; j < 16; j++) {
        int i = base + j * 256 + tid;
        if (i < N_EDGES) {
            int d = dst[i];
            int s = src[i];
            atomicAdd(&out_deg[s], 1);               // device atomic (src stream)
            int p = atomicAdd(&lc[d >> 8], 1);       // LDS atomic
            packed[p] = ((unsigned int)(d & 255) << 16) | (unsigned int)s;
        }
    }
}

// ---------------------------------------------------------------------------
// 4) Per-bucket CSR build: one block per coarse bucket (~4096 edges, <=8192).
// ---------------------------------------------------------------------------
__global__ __launch_bounds__(256) void bucket_csr(const unsigned int* __restrict__ packed,
                                                  const int* __restrict__ gh,
                                                  unsigned short* __restrict__ col16,
                                                  int* __restrict__ row_ptr,
                                                  float* __restrict__ nd) {
    __shared__ unsigned int ep[8192];
    __shared__ unsigned short lcol[8192];
    __shared__ int hist[256], cur[256], wsum[4];
    int t = threadIdx.x, b = blockIdx.x;
    int nb = gh[b * NBLK];
    int ne = (b < NB - 1) ? gh[(b + 1) * NBLK] : N_EDGES;
    int cnt = ne - nb;
    if (cnt > 8192) cnt = 8192;         // statistically unreachable guard
    hist[t] = 0;
    __syncthreads();
    for (int i = t; i < cnt; i += 256) {
        unsigned int e = packed[nb + i];
        ep[i] = e;
        atomicAdd(&hist[e >> 16], 1);
    }
    __syncthreads();
    int v = hist[t];
    int lane = t & 63, w = t >> 6;
    int x = v;
    #pragma unroll
    for (int d = 1; d < 64; d <<= 1) {
        int y = __shfl_up(x, d, 64);
        if (lane >= d) x += y;
    }
    if (lane == 63) wsum[w] = x;
    __syncthreads();
    int add = 0;
    #pragma unroll
    for (int i = 0; i < 4; i++) if (i < w) add += wsum[i];
    int excl = add + x - v;
    cur[t] = excl;
    int node = b * 256 + t;
    if (node < N_NODES) {
        row_ptr[node] = nb + excl;
        int id = v > 1 ? v : 1;
        nd[node] = 1.0f / sqrtf((float)id);
    }
    if (b == NB - 1 && t == 0) row_ptr[N_NODES] = N_EDGES;
    __syncthreads();
    for (int i = t; i < cnt; i += 256) {
        unsigned int e = ep[i];
        int p = atomicAdd(&cur[e >> 16], 1);         // LDS atomic
        lcol[p] = (unsigned short)(e & 0xFFFF);
    }
    __syncthreads();
    for (int i = t; i < cnt; i += 256) col16[nb + i] = lcol[i];
}

// ---------------------------------------------------------------------------
// 5) Prescale + slice: xs[p][node][16] = out_deg[node]^-1/2 * h[node][p*16..].
// ---------------------------------------------------------------------------
__global__ __launch_bounds__(256) void prescale_k(const float* __restrict__ h,
                                                  const int* __restrict__ out_deg,
                                                  float* __restrict__ out) {
    int i = blockIdx.x * 256 + threadIdx.x;      // over 1,600,000 float4s
    if (i < N_NODES * 32) {
        int node = i >> 5;
        int kg = i & 31;
        float4 v = ((const float4*)h)[i];
        int od = out_deg[node];
        float s = 1.0f / sqrtf((float)(od > 1 ? od : 1));
        int p = kg >> 2, q = kg & 3;
        ((float4*)out)[p * PLANE_F4 + node * 4 + q] =
            make_float4(v.x * s, v.y * s, v.z * s, v.w * s);
    }
}

// ---------------------------------------------------------------------------
// 6) Feature-sliced SpMM with LDS col staging (round-9 version, unchanged).
//    Shape LOCKED: grid 6256, 256 threads, slice=b&7, 64 nodes/blk.
// ---------------------------------------------------------------------------
__global__ __launch_bounds__(256) void spmm_k(const float* __restrict__ x,   // sliced
                                              const int* __restrict__ row_ptr,
                                              const unsigned short* __restrict__ col,
                                              const float* __restrict__ nd,
                                              float* __restrict__ out) {     // sliced
    __shared__ unsigned short lcol[LCOL_CAP];
    int b = blockIdx.x;
    int slice = b & 7;
    int n0b = (b >> 3) * 64;
    int nendb = n0b + 64; if (nendb > N_NODES) nendb = N_NODES;
    int e0 = row_ptr[n0b];
    int e1 = row_ptr[nendb];
    int cnt = e1 - e0;
    int staged = cnt < LCOL_CAP ? cnt : LCOL_CAP;
    for (int j = threadIdx.x; j < staged; j += 256) lcol[j] = col[e0 + j];
    __syncthreads();

    int node = n0b + (threadIdx.x >> 2);
    if (node >= N_NODES) return;
    int q = threadIdx.x & 3;
    int s = row_ptr[node];
    int e = row_ptr[node + 1];
    const float4* xp = (const float4*)x + slice * PLANE_F4;
    float4 a0 = make_float4(0.f, 0.f, 0.f, 0.f);
    float4 a1 = make_float4(0.f, 0.f, 0.f, 0.f);
    float4 a2 = make_float4(0.f, 0.f, 0.f, 0.f);
    float4 a3 = make_float4(0.f, 0.f, 0.f, 0.f);

    if (e - e0 <= staged) {
        const unsigned short* lc = lcol + (s - e0);
        int n = e - s;
        int i = 0;
        for (; i + 8 <= n; i += 8) {
            int c0 = lc[i],     c1 = lc[i + 1], c2 = lc[i + 2], c3 = lc[i + 3];
            int c4 = lc[i + 4], c5 = lc[i + 5], c6 = lc[i + 6], c7 = lc[i + 7];
            float4 h0 = xp[c0 * 4 + q];
            float4 h1 = xp[c1 * 4 + q];
            float4 h2 = xp[c2 * 4 + q];
            float4 h3 = xp[c3 * 4 + q];
            float4 h4 = xp[c4 * 4 + q];
            float4 h5 = xp[c5 * 4 + q];
            float4 h6 = xp[c6 * 4 + q];
            float4 h7 = xp[c7 * 4 + q];
            a0.x += h0.x; a0.y += h0.y; a0.z += h0.z; a0.w += h0.w;
            a1.x += h1.x; a1.y += h1.y; a1.z += h1.z; a1.w += h1.w;
            a2.x += h2.x; a2.y += h2.y; a2.z += h2.z; a2.w += h2.w;
            a3.x += h3.x; a3.y += h3.y; a3.z += h3.z; a3.w += h3.w;
            a0.x += h4.x; a0.y += h4.y; a0.z += h4.z; a0.w += h4.w;
            a1.x += h5.x; a1.y += h5.y; a1.z += h5.z; a1.w += h5.w;
            a2.x += h6.x; a2.y += h6.y; a2.z += h6.z; a2.w += h6.w;
            a3.x += h7.x; a3.y += h7.y; a3.z += h7.z; a3.w += h7.w;
        }
        for (; i + 4 <= n; i += 4) {
            int c0 = lc[i], c1 = lc[i + 1], c2 = lc[i + 2], c3 = lc[i + 3];
            float4 h0 = xp[c0 * 4 + q];
            float4 h1 = xp[c1 * 4 + q];
            float4 h2 = xp[c2 * 4 + q];
            float4 h3 = xp[c3 * 4 + q];
            a0.x += h0.x; a0.y += h0.y; a0.z += h0.z; a0.w += h0.w;
            a1.x += h1.x; a1.y += h1.y; a1.z += h1.z; a1.w += h1.w;
            a2.x += h2.x; a2.y += h2.y; a2.z += h2.z; a2.w += h2.w;
            a3.x += h3.x; a3.y += h3.y; a3.z += h3.z; a3.w += h3.w;
        }
        for (; i < n; i++) {
            float4 hv = xp[lc[i] * 4 + q];
            a0.x += hv.x; a0.y += hv.y; a0.z += hv.z; a0.w += hv.w;
        }
    } else {
        int i = s;
        for (; i + 4 <= e; i += 4) {
            int c0 = col[i], c1 = col[i + 1], c2 = col[i + 2], c3 = col[i + 3];
            float4 h0 = xp[c0 * 4 + q];
            float4 h1 = xp[c1 * 4 + q];
            float4 h2 = xp[c2 * 4 + q];
            float4 h3 = xp[c3 * 4 + q];
            a0.x += h0.x; a0.y += h0.y; a0.z += h0.z; a0.w += h0.w;
            a1.x += h1.x; a1.y += h1.y; a1.z += h1.z; a1.w += h1.w;
            a2.x += h2.x; a2.y += h2.y; a2.z += h2.z; a2.w += h2.w;
            a3.x += h3.x; a3.y += h3.y; a3.z += h3.z; a3.w += h3.w;
        }
        for (; i < e; i++) {
            float4 hv = xp[col[i] * 4 + q];
            a0.x += hv.x; a0.y += hv.y; a0.z += hv.z; a0.w += hv.w;
        }
    }
    float ndv = nd[node];
    ((float4*)out)[slice * PLANE_F4 + node * 4 + q] =
        make_float4((a0.x + a1.x + a2.x + a3.x) * ndv,
                    (a0.y + a1.y + a2.y + a3.y) * ndv,
                    (a0.z + a1.z + a2.z + a3.z) * ndv,
                    (a0.w + a1.w + a2.w + a3.w) * ndv);
}

// ---------------------------------------------------------------------------
// 7) GEMM + bias + ReLU. ROUND-14: r13's prefetch REVERTED (dynamic-indexed
//    pipeline defeated the scheduler: 137us, VALUBusy 11%). Geometry = r12
//    exact (64x128 tile, 128 threads, 8x8/thread, grid 782, AST=68). Single
//    variable: k-loop restructured as BATCH-4 -- 8 W-loads + 8 LDS-reads
//    issued back-to-back into static (compile-time-indexed) arrays, then a
//    256-FMA block. The grouped loads let the compiler's fine-grained
//    vmcnt/lgkmcnt start FMAs on first arrival with 15 loads in flight,
//    amortizing the ~200-300cy chain over 512cy of FMA issue.
//    MODE 0: out = odeg^-1/2 * relu(A@W+b), SLICED. MODE 1: normal layout.
// ---------------------------------------------------------------------------
template <int MODE>
__global__ __launch_bounds__(128) void gemm_relu_k(const float* __restrict__ A,  // sliced
                                                   const float* __restrict__ W,
                                                   const float* __restrict__ bias,
                                                   const int* __restrict__ odeg,
                                                   float* __restrict__ out) {
    __shared__ float As_t[128 * AST];   // 34,816 B: [k][r], padded stride 68
    int tid = threadIdx.x;
    int row0 = blockIdx.x * 64;
    const float4* A4 = (const float4*)A;
    const float4* W4 = (const float4*)W;

    // stage A: 64 rows x 128 k = 2048 float4s, 16 per thread
    #pragma unroll
    for (int it = 0; it < 16; it++) {
        int linear = it * 128 + tid;       // 0..2047
        int p = linear >> 8;               // plane 0..7
        int rem = linear & 255;
        int r = rem >> 2;                  // local row 0..63
        int q = rem & 3;                   // float4 within 16-float slice
        int row = row0 + r;
        float4 a = (row < N_NODES) ? A4[p * PLANE_F4 + row * 4 + q]
                                   : make_float4(0.f, 0.f, 0.f, 0.f);
        int kb = p * 16 + q * 4;
        As_t[(kb + 0) * AST + r] = a.x;
        As_t[(kb + 1) * AST + r] = a.y;
        As_t[(kb + 2) * AST + r] = a.z;
        As_t[(kb + 3) * AST + r] = a.w;
    }
    __syncthreads();

    int tc = tid & 15;    // col group: cols tc*8 .. +8 (of 128)
    int tr = tid >> 4;    // 0..7 : rows tr*8 .. +8 (of 64)
    float acc[8][8];
    #pragma unroll
    for (int r = 0; r < 8; r++)
        #pragma unroll
        for (int c = 0; c < 8; c++) acc[r][c] = 0.f;

    const float4* Wp = W4 + tc * 2;          // Wp[k*32] = W[k][tc*8..]
    const float*  Ab = As_t + tr * 8;        // Ab[k*AST] = A[k][tr*8..]

    for (int k0 = 0; k0 < 128; k0 += 4) {
        float4 wv0[4], wv1[4], av0[4], av1[4];
        #pragma unroll
        for (int u = 0; u < 4; u++) {
            wv0[u] = Wp[(k0 + u) * 32];
            wv1[u] = Wp[(k0 + u) * 32 + 1];
        }
        #pragma unroll
        for (int u = 0; u < 4; u++) {
            av0[u] = *(const float4*)(Ab + (k0 + u) * AST);
            av1[u] = *(const float4*)(Ab + (k0 + u) * AST + 4);
        }
        #pragma unroll
        for (int u = 0; u < 4; u++) {
            float av[8] = {av0[u].x, av0[u].y, av0[u].z, av0[u].w,
                           av1[u].x, av1[u].y, av1[u].z, av1[u].w};
            float wv[8] = {wv0[u].x, wv0[u].y, wv0[u].z, wv0[u].w,
                           wv1[u].x, wv1[u].y, wv1[u].z, wv1[u].w};
            #pragma unroll
            for (int rr = 0; rr < 8; rr++)
                #pragma unroll
                for (int cc = 0; cc < 8; cc++)
                    acc[rr][cc] = fmaf(av[rr], wv[cc], acc[rr][cc]);
        }
    }

    float4 bv0 = ((const float4*)bias)[tc * 2];
    float4 bv1 = ((const float4*)bias)[tc * 2 + 1];
    #pragma unroll
    for (int rr = 0; rr < 8; rr++) {
        int row = row0 + tr * 8 + rr;
        if (row < N_NODES) {
            float4 o0, o1;
            o0.x = fmaxf(acc[rr][0] + bv0.x, 0.f);
            o0.y = fmaxf(acc[rr][1] + bv0.y, 0.f);
            o0.z = fmaxf(acc[rr][2] + bv0.z, 0.f);
            o0.w = fmaxf(acc[rr][3] + bv0.w, 0.f);
            o1.x = fmaxf(acc[rr][4] + bv1.x, 0.f);
            o1.y = fmaxf(acc[rr][5] + bv1.y, 0.f);
            o1.z = fmaxf(acc[rr][6] + bv1.z, 0.f);
            o1.w = fmaxf(acc[rr][7] + bv1.w, 0.f);
            if (MODE == 0) {
                int od = odeg[row];
                float s = 1.0f / sqrtf((float)(od > 1 ? od : 1));
                o0.x *= s; o0.y *= s; o0.z *= s; o0.w *= s;
                o1.x *= s; o1.y *= s; o1.z *= s; o1.w *= s;
                int p = tc >> 1;
                int q0 = (tc & 1) * 2;
                ((float4*)out)[p * PLANE_F4 + row * 4 + q0] = o0;
                ((float4*)out)[p * PLANE_F4 + row * 4 + q0 + 1] = o1;
            } else {
                ((float4*)out)[row * 32 + tc * 2] = o0;
                ((float4*)out)[row * 32 + tc * 2 + 1] = o1;
            }
        }
    }
}

// ---------------------------------------------------------------------------
// 8) Fused projection + readout (unchanged).
// ---------------------------------------------------------------------------
__global__ __launch_bounds__(256) void proj_readout_k(const float* __restrict__ h,
                                                      const int* __restrict__ gid,
                                                      const float* __restrict__ Wm,
                                                      float* __restrict__ hgp,
                                                      int* __restrict__ gcnt) {
    __shared__ float Wmt[10 * 144];
    int tid = threadIdx.x;
    for (int i = tid; i < 1280; i += 256) {
        int k = i / 10, o = i % 10;
        Wmt[o * 144 + k + 4 * (k >> 5)] = Wm[i];
    }
    __syncthreads();

    int v = blockIdx.x * 64 + (tid >> 2);
    int quarter = tid & 3;
    int lane = tid & 63;

    float acc[D_OUT];
    #pragma unroll
    for (int o = 0; o < D_OUT; o++) acc[o] = 0.f;
    int g = -1;
    int cnt = 0;
    if (v < N_NODES) {
        g = gid[v];
        cnt = (quarter == 0) ? 1 : 0;
        const float4* h4 = (const float4*)h + v * 32 + quarter * 8;
        const float* wbase = Wmt + quarter * 36;
        #pragma unroll
        for (int kk = 0; kk < 8; kk++) {
            float4 hv = h4[kk];
            #pragma unroll
            for (int o = 0; o < D_OUT; o++) {
                float4 w = *(const float4*)(wbase + o * 144 + kk * 4);
                acc[o] += hv.x * w.x + hv.y * w.y + hv.z * w.z + hv.w * w.w;
            }
        }
    }

    #pragma unroll
    for (int d = 1; d < 64; d <<= 1) {
        int gp = __shfl_up(g, d, 64);
        int cp = __shfl_up(cnt, d, 64);
        bool take = (lane >= d) && (gp == g);
        #pragma unroll
        for (int o = 0; o < D_OUT; o++) {
            float ap = __shfl_up(acc[o], d, 64);
            if (take) acc[o] += ap;
        }
        if (take) cnt += cp;
    }
    int gn = __shfl_down(g, 1, 64);
    bool tail = (lane == 63) || (gn != g);
    if (tail && g >= 0) {
        #pragma unroll
        for (int o = 0; o < D_OUT; o++) atomicAdd(&hgp[g * D_OUT + o], acc[o]);
        if (cnt > 0) atomicAdd(&gcnt[g], cnt);
    }
}

// ---------------------------------------------------------------------------
// 9) Final: logits = hgp/cnt + bm ; log_softmax over axis 0 (graphs)
// ---------------------------------------------------------------------------
__global__ __launch_bounds__(512) void final_k(const float* __restrict__ hgp,
                                               const int* __restrict__ gcnt,
                                               const float* __restrict__ bm,
                                               float* __restrict__ out) {
    __shared__ float lg[N_GRAPHS * D_OUT];
    __shared__ float colm[D_OUT], colls[D_OUT];
    int tid = threadIdx.x;
    if (tid < N_GRAPHS * D_OUT) {
        int g = tid / D_OUT, o = tid % D_OUT;
        float c = (float)gcnt[g];
        lg[tid] = hgp[tid] / (c > 1.f ? c : 1.f) + bm[o];
    }
    __syncthreads();
    if (tid < D_OUT) {
        float m = -1e30f;
        for (int g = 0; g < N_GRAPHS; g++) m = fmaxf(m, lg[g * D_OUT + tid]);
        float s = 0.f;
        for (int g = 0; g < N_GRAPHS; g++) s += expf(lg[g * D_OUT + tid] - m);
        colm[tid] = m; colls[tid] = logf(s);
    }
    __syncthreads();
    if (tid < N_GRAPHS * D_OUT) {
        int o = tid % D_OUT;
        out[tid] = lg[tid] - colm[o] - colls[o];
    }
}

// ---------------------------------------------------------------------------
// Launch. packed[] aliases bufB head (dead before spmm#1 writes bufB).
// No memset dispatch: part_hist zeroes out_deg+gcnt+hgp.
// Total footprint 53,556,128 B.
// ---------------------------------------------------------------------------
extern "C" void kernel_launch(void* const* d_in, const int* in_sizes, int n_in,
                              void* d_out, int out_size, void* d_ws, size_t ws_size,
                              hipStream_t stream) {
    const float* h_in = (const float*)d_in[0];
    const int*   src  = (const int*)d_in[1];
    const int*   dst  = (const int*)d_in[2];
    const int*   gid  = (const int*)d_in[3];
    const float* W1 = (const float*)d_in[4];  const float* b1 = (const float*)d_in[5];
    const float* W2 = (const float*)d_in[6];  const float* b2 = (const float*)d_in[7];
    const float* W3 = (const float*)d_in[8];  const float* b3 = (const float*)d_in[9];
    const float* Wm = (const float*)d_in[10]; const float* bm = (const float*)d_in[11];

    char* ws = (char*)d_ws;
    int*            row_ptr = (int*)(ws + 0);                     // 50001 ints (pad 200,032)
    unsigned short* col16   = (unsigned short*)(ws + 200032);     // 1,600,000 B
    float*          nd      = (float*)(ws + 1800032);             // 200,000 B
    int*            out_deg = (int*)(ws + 2000032);               // 200,000 B  } zeroed
    int*            gcnt    = (int*)(ws + 2200032);               // 256 B      } by
    float*          hgp     = (float*)(ws + 2200288);             // 2,048 B    } part_hist
    int*            gh      = (int*)(ws + 2202464);               // 153,664 B
    float*          bufA    = (float*)(ws + 2356128);             // 25.6 MB
    float*          bufB    = (float*)(ws + 27956128);            // 25.6 MB -> 53,556,128
    unsigned int*   packed  = (unsigned int*)bufB;                // 3.2 MB alias

    part_hist<<<NBLK, 256, 0, stream>>>(dst, gh, out_deg);
    part_scan<<<1, 1024, 0, stream>>>(gh);
    part_scatter<<<NBLK, 256, 0, stream>>>(src, dst, gh, packed, out_deg);
    bucket_csr<<<NB, 256, 0, stream>>>(packed, gh, col16, row_ptr, nd);
    prescale_k<<<6250, 256, 0, stream>>>(h_in, out_deg, bufA);

    spmm_k<<<6256, 256, 0, stream>>>(bufA, row_ptr, col16, nd, bufB);
    gemm_relu_k<0><<<782, 128, 0, stream>>>(bufB, W1, b1, out_deg, bufA);
    spmm_k<<<6256, 256, 0, stream>>>(bufA, row_ptr, col16, nd, bufB);
    gemm_relu_k<0><<<782, 128, 0, stream>>>(bufB, W2, b2, out_deg, bufA);
    spmm_k<<<6256, 256, 0, stream>>>(bufA, row_ptr, col16, nd, bufB);
    gemm_relu_k<1><<<782, 128, 0, stream>>>(bufB, W3, b3, out_deg, bufA);

    proj_readout_k<<<782, 256, 0, stream>>>(bufA, gid, Wm, hgp, gcnt);
    final_k<<<1, 512, 0, stream>>>(hgp, gcnt, bm, (float*)d_out);
}